// Round 4
// baseline (3344.598 us; speedup 1.0000x reference)
//
#include <hip/hip_runtime.h>

// PlayerPerformanceGNN: 2-layer GCN (32->16->8) + mean-pool + linear (8->5)
// N=1M, E=16M, G=10k.
// Round 3 (on top of R2 bucket pipeline):
//   - dis folded into node features: hs = dis*h written by the matmuls, so the
//     edge loop is pure gather+LDS-add (kills the random per-edge dis[src]
//     fetch that was ~1 GB of conv1's 2.18 GB FETCH_SIZE in R2)
//   - 8-deep edge unroll in convs: 32 outstanding 64B gathers/wave (was ~8)
//   - conv2 epilogue pools via a 32-graph LDS window (batch is sorted):
//     ~0.3M global atomics instead of 9M

namespace {

constexpr int F_IN = 32, F_H1 = 16, F_H2 = 8, N_CLS = 5;
constexpr int BB = 10, NPB = 1 << BB;   // nodes per bucket
constexpr int MAXB = 1024;              // bucket-table size (N <= 2^20)
constexpr int CHUNK = 12288;            // edges per binscatter block (48KB stage)

// ---------------- dense matmuls (write hs = dis * (in @ W)) ----------------

__global__ void k_mm1(const float* __restrict__ x, const float* __restrict__ W,
                      const float* __restrict__ dis, float* __restrict__ h, int N) {
  __shared__ float w[F_IN * F_H1];
  for (int k = threadIdx.x; k < F_IN * F_H1; k += blockDim.x) w[k] = W[k];
  __syncthreads();
  int i = blockIdx.x * blockDim.x + threadIdx.x;
  if (i >= N) return;
  const float4* xr = reinterpret_cast<const float4*>(x + (size_t)i * F_IN);
  float acc[F_H1];
#pragma unroll
  for (int f = 0; f < F_H1; ++f) acc[f] = 0.f;
#pragma unroll
  for (int k4 = 0; k4 < F_IN / 4; ++k4) {
    float4 v = xr[k4];
    float vv[4] = {v.x, v.y, v.z, v.w};
#pragma unroll
    for (int j = 0; j < 4; ++j) {
      const float* wr = &w[(k4 * 4 + j) * F_H1];
#pragma unroll
      for (int f = 0; f < F_H1; ++f) acc[f] = fmaf(vv[j], wr[f], acc[f]);
    }
  }
  float s = dis ? dis[i] : 1.0f;
  float4* hr = reinterpret_cast<float4*>(h + (size_t)i * F_H1);
#pragma unroll
  for (int q = 0; q < F_H1 / 4; ++q)
    hr[q] = make_float4(s * acc[q * 4], s * acc[q * 4 + 1], s * acc[q * 4 + 2],
                        s * acc[q * 4 + 3]);
}

__global__ void k_mm2(const float* __restrict__ in, const float* __restrict__ W,
                      const float* __restrict__ dis, float* __restrict__ h, int N) {
  __shared__ float w[F_H1 * F_H2];
  for (int k = threadIdx.x; k < F_H1 * F_H2; k += blockDim.x) w[k] = W[k];
  __syncthreads();
  int i = blockIdx.x * blockDim.x + threadIdx.x;
  if (i >= N) return;
  const float4* xr = reinterpret_cast<const float4*>(in + (size_t)i * F_H1);
  float acc[F_H2];
#pragma unroll
  for (int f = 0; f < F_H2; ++f) acc[f] = 0.f;
#pragma unroll
  for (int k4 = 0; k4 < F_H1 / 4; ++k4) {
    float4 v = xr[k4];
    float vv[4] = {v.x, v.y, v.z, v.w};
#pragma unroll
    for (int j = 0; j < 4; ++j) {
      const float* wr = &w[(k4 * 4 + j) * F_H2];
#pragma unroll
      for (int f = 0; f < F_H2; ++f) acc[f] = fmaf(vv[j], wr[f], acc[f]);
    }
  }
  float s = dis ? dis[i] : 1.0f;
  float4* hr = reinterpret_cast<float4*>(h + (size_t)i * F_H2);
#pragma unroll
  for (int q = 0; q < F_H2 / 4; ++q)
    hr[q] = make_float4(s * acc[q * 4], s * acc[q * 4 + 1], s * acc[q * 4 + 2],
                        s * acc[q * 4 + 3]);
}

__global__ void k_final(const float* __restrict__ pooled, const float* __restrict__ cnts,
                        const float* __restrict__ Wl, const float* __restrict__ bl,
                        float* __restrict__ out, int total) {
  int gid = blockIdx.x * blockDim.x + threadIdx.x;
  if (gid >= total) return;
  int g = gid / N_CLS, c = gid % N_CLS;
  float s = 0.f;
#pragma unroll
  for (int f = 0; f < F_H2; ++f) s += pooled[g * F_H2 + f] * Wl[f * N_CLS + c];
  out[gid] = s / fmaxf(cnts[g], 1.f) + bl[c];
}

// ---------------- bucket build (unchanged from R2) ----------------

__global__ void k_hist(const int* __restrict__ dst, int* __restrict__ bcnt,
                       int E, int nbuck) {
  __shared__ int h[MAXB];
  for (int i = threadIdx.x; i < MAXB; i += blockDim.x) h[i] = 0;
  __syncthreads();
  for (int e = blockIdx.x * blockDim.x + threadIdx.x; e < E;
       e += gridDim.x * blockDim.x)
    atomicAdd(&h[dst[e] >> BB], 1);
  __syncthreads();
  for (int i = threadIdx.x; i < nbuck; i += blockDim.x)
    if (h[i]) atomicAdd(&bcnt[i], h[i]);
}

__global__ void k_bscan(const int* __restrict__ bcnt, int* __restrict__ bbase,
                        int* __restrict__ bcur, int nbuck, int E) {
  __shared__ int s[MAXB];
  int t = threadIdx.x;
  int v = (t < nbuck) ? bcnt[t] : 0;
  s[t] = v;
  __syncthreads();
  for (int off = 1; off < MAXB; off <<= 1) {
    int x = (t >= off) ? s[t - off] : 0;
    __syncthreads();
    s[t] += x;
    __syncthreads();
  }
  int ex = s[t] - v;
  if (t < nbuck) { bbase[t] = ex; bcur[t] = ex; }
  if (t == 0) bbase[nbuck] = E;
}

__global__ __launch_bounds__(256)
void k_binscatter(const int* __restrict__ dst, const int* __restrict__ src,
                  int* __restrict__ bcur, int* __restrict__ packed, int E) {
  __shared__ int hist[MAXB];
  __shared__ int sbase[MAXB];
  __shared__ int lcur[MAXB];
  __shared__ int stg[CHUNK];
  __shared__ int stmp[256];
  int t = threadIdx.x;
  int c0 = blockIdx.x * CHUNK;
  int n = min(CHUNK, E - c0);
  for (int i = t; i < MAXB; i += 256) hist[i] = 0;
  __syncthreads();
  for (int j = t; j < n; j += 256) atomicAdd(&hist[dst[c0 + j] >> BB], 1);
  __syncthreads();
  int v[4], sum = 0;
  int b4 = t * 4;
#pragma unroll
  for (int k = 0; k < 4; ++k) { v[k] = hist[b4 + k]; sum += v[k]; }
  stmp[t] = sum;
  __syncthreads();
  for (int off = 1; off < 256; off <<= 1) {
    int x = (t >= off) ? stmp[t - off] : 0;
    __syncthreads();
    stmp[t] += x;
    __syncthreads();
  }
  int run = stmp[t] - sum;
#pragma unroll
  for (int k = 0; k < 4; ++k) { sbase[b4 + k] = run; lcur[b4 + k] = run; run += v[k]; }
  __syncthreads();
  for (int i = t; i < MAXB; i += 256) {
    int c = hist[i];
    if (c) hist[i] = atomicAdd(&bcur[i], c);
  }
  __syncthreads();
  for (int j = t; j < n; j += 256) {
    int d = dst[c0 + j], s = src[c0 + j];
    int b = d >> BB;
    int p = atomicAdd(&lcur[b], 1);
    stg[p] = ((d & (NPB - 1)) << 20) | s;
  }
  __syncthreads();
  for (int j = t; j < n; j += 256) {
    int lo = 0, hi = MAXB - 1;
    while (lo < hi) {
      int mid = (lo + hi + 1) >> 1;
      if (sbase[mid] <= j) lo = mid; else hi = mid - 1;
    }
    packed[hist[lo] + (j - sbase[lo])] = stg[j];
  }
}

__global__ void k_dis_b(const int* __restrict__ bbase, const int* __restrict__ packed,
                        float* __restrict__ dis, int N) {
  __shared__ int cnt[NPB];
  int t = threadIdx.x;
  for (int i = t; i < NPB; i += blockDim.x) cnt[i] = 0;
  __syncthreads();
  int b = blockIdx.x;
  int beg = bbase[b], end = bbase[b + 1];
  for (int e = beg + t; e < end; e += blockDim.x)
    atomicAdd(&cnt[packed[e] >> 20], 1);
  __syncthreads();
  int node0 = b << BB;
  for (int i = t; i < NPB; i += blockDim.x) {
    int node = node0 + i;
    if (node < N) dis[node] = rsqrtf((float)cnt[i] + 1.0f);
  }
}

// ---------------- bucketed conv (LDS accumulate, hs pre-scaled) ----------------
// out_i = relu( dis_i * (sum_{j->i} hs_j + hs_i) + b ),  hs = dis*h

template <int F>
__global__ __launch_bounds__(512)
void k_conv(const int* __restrict__ bbase, const int* __restrict__ packed,
            const float* __restrict__ dis, const float* __restrict__ hs,
            const float* __restrict__ bias, float* __restrict__ out, int N) {
  __shared__ float acc[NPB * F];  // F=16: 64KB
  int t = threadIdx.x;
  for (int i = t; i < NPB * F; i += 512) acc[i] = 0.f;
  __syncthreads();
  int b = blockIdx.x;
  int beg = bbase[b], end = bbase[b + 1];
  const int EPI = 512 / F;
  int f = t % F, eg = t / F;
  constexpr int U = 8;
  int e = beg + eg;
  for (; e + (U - 1) * EPI < end; e += U * EPI) {
    int p[U];
    float m[U];
#pragma unroll
    for (int k = 0; k < U; ++k) p[k] = packed[e + k * EPI];
#pragma unroll
    for (int k = 0; k < U; ++k)
      m[k] = hs[(size_t)(p[k] & 0xFFFFF) * F + f];
#pragma unroll
    for (int k = 0; k < U; ++k)
      atomicAdd(&acc[(p[k] >> 20) * F + f], m[k]);
  }
  for (; e < end; e += EPI) {
    int p = packed[e];
    atomicAdd(&acc[(p >> 20) * F + f], hs[(size_t)(p & 0xFFFFF) * F + f]);
  }
  __syncthreads();
  int node0 = b << BB;
  for (int i = t; i < NPB * F; i += 512) {
    int node = node0 + i / F;
    if (node >= N) continue;
    int ff = i % F;
    float v = fmaf(dis[node], acc[i] + hs[(size_t)node * F + ff], bias[ff]);
    out[(size_t)node * F + ff] = fmaxf(v, 0.f);
  }
}

// conv2 + mean-pool epilogue via LDS graph window (batch sorted)
__global__ __launch_bounds__(512)
void k_conv_pool(const int* __restrict__ bbase, const int* __restrict__ packed,
                 const float* __restrict__ dis, const float* __restrict__ hs,
                 const float* __restrict__ bias, const int* __restrict__ batch,
                 float* __restrict__ pooled, float* __restrict__ cnts, int N, int G) {
  constexpr int F = F_H2;
  constexpr int GW = 32;          // graph window per bucket
  __shared__ float acc[NPB * F];  // 32KB
  __shared__ float pacc[GW * F];
  __shared__ float pcnt[GW];
  __shared__ int gmin_s;
  int t = threadIdx.x;
  for (int i = t; i < NPB * F; i += 512) acc[i] = 0.f;
  for (int i = t; i < GW * F; i += 512) pacc[i] = 0.f;
  if (t < GW) pcnt[t] = 0.f;
  int b = blockIdx.x;
  int node0 = b << BB;
  if (t == 0) gmin_s = batch[node0];
  __syncthreads();
  int beg = bbase[b], end = bbase[b + 1];
  const int EPI = 512 / F;
  int f = t % F, eg = t / F;
  constexpr int U = 8;
  int e = beg + eg;
  for (; e + (U - 1) * EPI < end; e += U * EPI) {
    int p[U];
    float m[U];
#pragma unroll
    for (int k = 0; k < U; ++k) p[k] = packed[e + k * EPI];
#pragma unroll
    for (int k = 0; k < U; ++k)
      m[k] = hs[(size_t)(p[k] & 0xFFFFF) * F + f];
#pragma unroll
    for (int k = 0; k < U; ++k)
      atomicAdd(&acc[(p[k] >> 20) * F + f], m[k]);
  }
  for (; e < end; e += EPI) {
    int p = packed[e];
    atomicAdd(&acc[(p >> 20) * F + f], hs[(size_t)(p & 0xFFFFF) * F + f]);
  }
  __syncthreads();
  int gmin = gmin_s;
  for (int i = t; i < NPB * F; i += 512) {
    int node = node0 + i / F;
    if (node >= N) continue;
    int ff = i % F;
    float v = fmaf(dis[node], acc[i] + hs[(size_t)node * F + ff], bias[ff]);
    v = fmaxf(v, 0.f);
    int g = batch[node];
    int idx = g - gmin;
    if (idx < GW) {
      atomicAdd(&pacc[idx * F + ff], v);
      if (ff == 0) atomicAdd(&pcnt[idx], 1.0f);
    } else {  // pathological clustering fallback
      atomicAdd(&pooled[g * F + ff], v);
      if (ff == 0) atomicAdd(&cnts[g], 1.0f);
    }
  }
  __syncthreads();
  for (int i = t; i < GW * F; i += 512) {
    int g = gmin + i / F;
    float v = pacc[i];
    if (g < G && v != 0.f) atomicAdd(&pooled[g * F + i % F], v);
  }
  if (t < GW) {
    int g = gmin + t;
    float c = pcnt[t];
    if (g < G && c > 0.f) atomicAdd(&cnts[g], c);
  }
}

// ---------------- fallback (round-0 scatter atomics) ----------------

__global__ void k_deg(const int* __restrict__ dst, float* __restrict__ deg, int E) {
  int e = blockIdx.x * blockDim.x + threadIdx.x;
  if (e < E) atomicAdd(&deg[dst[e]], 1.0f);
}
__global__ void k_dis(float* __restrict__ d, int N) {
  int i = blockIdx.x * blockDim.x + threadIdx.x;
  if (i < N) d[i] = rsqrtf(d[i] + 1.0f);
}
template <int F>
__global__ void k_edge(const int* __restrict__ src, const int* __restrict__ dst,
                       const float* __restrict__ dis, const float* __restrict__ h,
                       float* __restrict__ agg, int total) {
  int gid = blockIdx.x * blockDim.x + threadIdx.x;
  if (gid >= total) return;
  int e = gid / F, f = gid % F;
  int s = src[e], d = dst[e];
  atomicAdd(&agg[d * F + f], h[s * F + f] * dis[s] * dis[d]);
}
template <int F>
__global__ void k_combine(const float* __restrict__ h, const float* __restrict__ dis,
                          const float* __restrict__ b, float* __restrict__ agg, int total) {
  int gid = blockIdx.x * blockDim.x + threadIdx.x;
  if (gid >= total) return;
  int i = gid / F, f = gid % F;
  float di = dis[i];
  agg[gid] = fmaxf(agg[gid] + h[gid] * di * di + b[f], 0.f);
}
__global__ void k_combine_pool_fb(const float* __restrict__ h2, const float* __restrict__ agg2,
                                  const float* __restrict__ dis, const float* __restrict__ b,
                                  const int* __restrict__ batch, float* __restrict__ pooled,
                                  float* __restrict__ cnts, int total) {
  int gid = blockIdx.x * blockDim.x + threadIdx.x;
  if (gid >= total) return;
  int i = gid >> 3, f = gid & 7;
  float di = dis[i];
  float v = fmaxf(agg2[gid] + h2[gid] * di * di + b[f], 0.f);
  int g = batch[i];
  atomicAdd(&pooled[g * F_H2 + f], v);
  if (f == 0) atomicAdd(&cnts[g], 1.0f);
}

}  // namespace

extern "C" void kernel_launch(void* const* d_in, const int* in_sizes, int n_in,
                              void* d_out, int out_size, void* d_ws, size_t ws_size,
                              hipStream_t stream) {
  const float* x   = (const float*)d_in[0];
  const int* ei    = (const int*)d_in[1];
  const int* batch = (const int*)d_in[2];
  const float* W1 = (const float*)d_in[4];
  const float* b1 = (const float*)d_in[5];
  const float* W2 = (const float*)d_in[6];
  const float* b2 = (const float*)d_in[7];
  const float* Wl = (const float*)d_in[8];
  const float* bl = (const float*)d_in[9];

  const int N = in_sizes[0] / F_IN;   // 1,000,000
  const int E = in_sizes[1] / 2;      // 16,000,000
  const int G = out_size / N_CLS;     // 10,000
  const int* src  = ei;
  const int* dstp = ei + E;

  const int BLK = 256;
  const int nbuck = (N + NPB - 1) >> BB;

  size_t need = (size_t)(3 * MAXB + 8) * 4
              + (size_t)E * 4
              + (size_t)N * 4
              + (size_t)N * F_H1 * 4
              + (size_t)N * F_H1 * 4
              + (size_t)G * (F_H2 + 1) * 4 + 1024;

  if (N <= (1 << 20) && nbuck <= MAXB && ws_size >= need) {
    char* p = (char*)d_ws;
    int*   bcnt   = (int*)p;    p += (size_t)MAXB * 4;
    int*   bbase  = (int*)p;    p += (size_t)(MAXB + 4) * 4;
    int*   bcur   = (int*)p;    p += (size_t)MAXB * 4;
    int*   packed = (int*)p;    p += (size_t)E * 4;
    float* dis    = (float*)p;  p += (size_t)N * 4;
    float* H      = (float*)p;  p += (size_t)N * F_H1 * 4;
    float* O      = (float*)p;  p += (size_t)N * F_H1 * 4;
    float* pooled = (float*)p;  p += (size_t)G * F_H2 * 4;
    float* cnts   = (float*)p;

    hipMemsetAsync(bcnt, 0, (size_t)MAXB * 4, stream);
    hipMemsetAsync(pooled, 0, ((size_t)G * F_H2 + G) * 4, stream);

    // bucket build + dis
    k_hist<<<2048, BLK, 0, stream>>>(dstp, bcnt, E, nbuck);
    k_bscan<<<1, MAXB, 0, stream>>>(bcnt, bbase, bcur, nbuck, E);
    k_binscatter<<<(E + CHUNK - 1) / CHUNK, BLK, 0, stream>>>(dstp, src, bcur, packed, E);
    k_dis_b<<<nbuck, BLK, 0, stream>>>(bbase, packed, dis, N);

    // conv1 (H = dis * (x@W1))
    k_mm1<<<(N + BLK - 1) / BLK, BLK, 0, stream>>>(x, W1, dis, H, N);
    k_conv<F_H1><<<nbuck, 512, 0, stream>>>(bbase, packed, dis, H, b1, O, N);
    // conv2 (H = dis * (out1@W2))
    k_mm2<<<(N + BLK - 1) / BLK, BLK, 0, stream>>>(O, W2, dis, H, N);
    k_conv_pool<<<nbuck, 512, 0, stream>>>(bbase, packed, dis, H, b2, batch,
                                           pooled, cnts, N, G);

    k_final<<<(G * N_CLS + BLK - 1) / BLK, BLK, 0, stream>>>(
        pooled, cnts, Wl, bl, (float*)d_out, G * N_CLS);
    return;
  }

  // ---------- fallback: round-0 scatter-atomic path ----------
  float* ws = (float*)d_ws;
  float* dis    = ws;
  float* A      = ws + N;
  float* B      = A + (size_t)N * F_H1;
  float* h2     = A;
  float* agg2   = A + (size_t)N * F_H2;
  float* pooled = B + (size_t)N * F_H1;
  float* cnts   = pooled + (size_t)G * F_H2;

  hipMemsetAsync(dis, 0, (size_t)N * sizeof(float), stream);
  hipMemsetAsync(B, 0, (size_t)N * F_H1 * sizeof(float), stream);
  hipMemsetAsync(pooled, 0, ((size_t)G * F_H2 + G) * sizeof(float), stream);

  k_deg<<<(E + BLK - 1) / BLK, BLK, 0, stream>>>(dstp, dis, E);
  k_dis<<<(N + BLK - 1) / BLK, BLK, 0, stream>>>(dis, N);
  k_mm1<<<(N + BLK - 1) / BLK, BLK, 0, stream>>>(x, W1, nullptr, A, N);
  k_edge<F_H1><<<(E * F_H1 + BLK - 1) / BLK, BLK, 0, stream>>>(src, dstp, dis, A, B, E * F_H1);
  k_combine<F_H1><<<(N * F_H1 + BLK - 1) / BLK, BLK, 0, stream>>>(A, dis, b1, B, N * F_H1);
  hipMemsetAsync(agg2, 0, (size_t)N * F_H2 * sizeof(float), stream);
  k_mm2<<<(N + BLK - 1) / BLK, BLK, 0, stream>>>(B, W2, nullptr, h2, N);
  k_edge<F_H2><<<(E * F_H2 + BLK - 1) / BLK, BLK, 0, stream>>>(src, dstp, dis, h2, agg2, E * F_H2);
  k_combine_pool_fb<<<(N * F_H2 + BLK - 1) / BLK, BLK, 0, stream>>>(
      h2, agg2, dis, b2, batch, pooled, cnts, N * F_H2);
  k_final<<<(G * N_CLS + BLK - 1) / BLK, BLK, 0, stream>>>(
      pooled, cnts, Wl, bl, (float*)d_out, G * N_CLS);
}